// Round 7
// baseline (1902.093 us; speedup 1.0000x reference)
//
#include <hip/hip_runtime.h>
#include <math.h>

#define DIM 64
#define NT 4
#define NR 8
#define SRC_MASK 0x00FFFFFF
// tmeta layout: [0..3]=tcnt  [4..7]=tbase  [8..11]=tfill  [12]=padded_total

__global__ void init_cnt(int* __restrict__ cnt, int* __restrict__ cnt2, int N) {
    int i = blockIdx.x * blockDim.x + threadIdx.x;
    if (i < N) { cnt[i] = 0; cnt2[i] = 0; }
}

__global__ void init_order(int* __restrict__ order, int* __restrict__ tm, int cap) {
    int i = blockIdx.x * blockDim.x + threadIdx.x;
    if (i < cap) order[i] = -1;
    if (i < 16) tm[i] = 0;
}

// ---- per-wave ballot histogram of node types ----
__global__ void type_count(const int* __restrict__ ntype, int* __restrict__ tm, int N) {
    int i = blockIdx.x * blockDim.x + threadIdx.x;
    int t = (i < N) ? ntype[i] : -1;
    int lane = threadIdx.x & 63;
    #pragma unroll
    for (int tt = 0; tt < NT; tt++) {
        unsigned long long m = __ballot(t == tt);
        int c = __popcll(m);
        if (c && lane == (__ffsll((long long)m) - 1)) atomicAdd(&tm[tt], c);
    }
}

__global__ void type_scan(int* __restrict__ tm) {
    if (threadIdx.x == 0 && blockIdx.x == 0) {
        int b = 0;
        for (int t = 0; t < NT; t++) { tm[4 + t] = b; b += ((tm[t] + 63) >> 6) << 6; }
        tm[12] = b;
    }
}

__global__ void type_scatter(const int* __restrict__ ntype, int* __restrict__ tm,
                             int* __restrict__ order, int N) {
    int i = blockIdx.x * blockDim.x + threadIdx.x;
    int t = (i < N) ? ntype[i] : -1;
    int lane = threadIdx.x & 63;
    #pragma unroll
    for (int tt = 0; tt < NT; tt++) {
        unsigned long long m = __ballot(t == tt);
        int c = __popcll(m);
        if (!c) continue;
        int ldr = __ffsll((long long)m) - 1;
        int base = 0;
        if (lane == ldr) base = atomicAdd(&tm[8 + tt], c);
        base = __shfl(base, ldr, 64);
        if (t == tt) {
            int rank = __popcll(m & ((1ull << lane) - 1ull));
            order[tm[4 + tt] + base + rank] = i;
        }
    }
}

// ---- typed K/Q/V projection: 64-node tile, one 16KB W buffer, loop 3 mats ----
__global__ void proj_typed(const float* __restrict__ h, const int* __restrict__ ntype,
                           const int* __restrict__ order, const int* __restrict__ tm,
                           const float* __restrict__ Wk, const float* __restrict__ Wq,
                           const float* __restrict__ Wv,
                           float* __restrict__ k, float* __restrict__ q,
                           float* __restrict__ v, int N) {
    __shared__ float xs[64][68];
    __shared__ float wsm[64][64];
    int t  = threadIdx.x;
    int n0 = blockIdx.x * 64;
    if (n0 >= tm[12]) return;
    int first = order[n0];
    if (first < 0) return;
    int ty = ntype[first];

    #pragma unroll
    for (int i = 0; i < 4; i++) {
        int idx = t + 256 * i;
        int row = idx >> 4, c4 = idx & 15;
        int gn = order[n0 + row];
        float4 xv = make_float4(0.f, 0.f, 0.f, 0.f);
        if (gn >= 0) xv = ((const float4*)(h + (size_t)gn * DIM))[c4];
        ((float4*)&xs[row][0])[c4] = xv;
    }

    const float* Ws[3] = { Wk + (size_t)ty * DIM * DIM,
                           Wq + (size_t)ty * DIM * DIM,
                           Wv + (size_t)ty * DIM * DIM };
    float* outs[3] = { k, q, v };

    int og  = t & 15;
    int ng4 = (t >> 4) * 4;
    int g0 = order[n0 + ng4 + 0];
    int g1 = order[n0 + ng4 + 1];
    int g2 = order[n0 + ng4 + 2];
    int g3 = order[n0 + ng4 + 3];

    for (int mm = 0; mm < 3; mm++) {
        const float4* wg = (const float4*)Ws[mm];
        float4* wl = (float4*)&wsm[0][0];
        __syncthreads();
        #pragma unroll
        for (int i = 0; i < 4; i++) wl[t + 256 * i] = wg[t + 256 * i];
        __syncthreads();
        float4 a0 = make_float4(0.f,0.f,0.f,0.f), a1 = a0, a2 = a0, a3 = a0;
        #pragma unroll 8
        for (int d = 0; d < DIM; d++) {
            float4 wv = ((const float4*)&wsm[d][0])[og];
            float x0 = xs[ng4 + 0][d];
            float x1 = xs[ng4 + 1][d];
            float x2 = xs[ng4 + 2][d];
            float x3 = xs[ng4 + 3][d];
            a0.x = fmaf(x0, wv.x, a0.x); a0.y = fmaf(x0, wv.y, a0.y);
            a0.z = fmaf(x0, wv.z, a0.z); a0.w = fmaf(x0, wv.w, a0.w);
            a1.x = fmaf(x1, wv.x, a1.x); a1.y = fmaf(x1, wv.y, a1.y);
            a1.z = fmaf(x1, wv.z, a1.z); a1.w = fmaf(x1, wv.w, a1.w);
            a2.x = fmaf(x2, wv.x, a2.x); a2.y = fmaf(x2, wv.y, a2.y);
            a2.z = fmaf(x2, wv.z, a2.z); a2.w = fmaf(x2, wv.w, a2.w);
            a3.x = fmaf(x3, wv.x, a3.x); a3.y = fmaf(x3, wv.y, a3.y);
            a3.z = fmaf(x3, wv.z, a3.z); a3.w = fmaf(x3, wv.w, a3.w);
        }
        float* ob = outs[mm];
        if (g0 >= 0) ((float4*)(ob + (size_t)g0 * DIM))[og] = a0;
        if (g1 >= 0) ((float4*)(ob + (size_t)g1 * DIM))[og] = a1;
        if (g2 >= 0) ((float4*)(ob + (size_t)g2 * DIM))[og] = a2;
        if (g3 >= 0) ((float4*)(ob + (size_t)g3 * DIM))[og] = a3;
    }
}

// ---------------- CSR build ----------------
__global__ void hist_kernel(const int* __restrict__ dst, int* __restrict__ cnt, int E) {
    int e = blockIdx.x * blockDim.x + threadIdx.x;
    if (e < E) atomicAdd(&cnt[dst[e]], 1);
}

__global__ void scan1(const int* __restrict__ cnt, int* __restrict__ off,
                      int* __restrict__ bsum, int N) {
    __shared__ int buf[1024];
    int tid = threadIdx.x;
    int i = blockIdx.x * 1024 + tid;
    int x = (i < N) ? cnt[i] : 0;
    buf[tid] = x;
    __syncthreads();
    for (int s = 1; s < 1024; s <<= 1) {
        int t = (tid >= s) ? buf[tid - s] : 0;
        __syncthreads();
        buf[tid] += t;
        __syncthreads();
    }
    if (i < N) off[i] = buf[tid] - x;
    if (tid == 1023) bsum[blockIdx.x] = buf[1023];
}

__global__ void scan2(int* __restrict__ bsum, int nb) {
    __shared__ int buf[1024];
    __shared__ int carry;
    int tid = threadIdx.x;
    if (tid == 0) carry = 0;
    __syncthreads();
    for (int base = 0; base < nb; base += 1024) {
        int i = base + tid;
        int x = (i < nb) ? bsum[i] : 0;
        buf[tid] = x;
        __syncthreads();
        for (int s = 1; s < 1024; s <<= 1) {
            int t = (tid >= s) ? buf[tid - s] : 0;
            __syncthreads();
            buf[tid] += t;
            __syncthreads();
        }
        if (i < nb) bsum[i] = carry + buf[tid] - x;
        __syncthreads();
        if (tid == 1023) carry += buf[1023];
        __syncthreads();
    }
}

__global__ void scan3(int* __restrict__ off, const int* __restrict__ bsum, int N, int E) {
    int i = blockIdx.x * 1024 + threadIdx.x;
    if (i < N) off[i] += bsum[blockIdx.x];
    if (i == 0) off[N] = E;
}

__global__ void scatter_kernel(const int* __restrict__ src, const int* __restrict__ dst,
                               const int* __restrict__ et, const int* __restrict__ off,
                               int* __restrict__ cnt2, int* __restrict__ se, int E) {
    int e = blockIdx.x * blockDim.x + threadIdx.x;
    if (e >= E) return;
    int d = dst[e];
    int p = off[d] + atomicAdd(&cnt2[d], 1);
    se[p] = (et[e] << 24) | src[e];
}

// ---- fused score: per 64-dst block, loop r: t = q_tile@A_r in LDS, walk edges ----
__global__ void score_fused(const float* __restrict__ q, const float* __restrict__ k,
                            const int* __restrict__ se, const int* __restrict__ off,
                            const float* __restrict__ A, const float* __restrict__ rel_pri,
                            float* __restrict__ ex, float* __restrict__ den, int N) {
    __shared__ float qs[64][68];
    __shared__ float As[64][64];
    __shared__ float ts[64][68];
    int t  = threadIdx.x;
    int n0 = blockIdx.x * 64;

    // stage q tile
    #pragma unroll
    for (int i = 0; i < 4; i++) {
        int idx = t + 256 * i;
        int row = idx >> 4, c4 = idx & 15;
        int gn = n0 + row;
        float4 xv = make_float4(0.f, 0.f, 0.f, 0.f);
        if (gn < N) xv = ((const float4*)(q + (size_t)gn * DIM))[c4];
        ((float4*)&qs[row][0])[c4] = xv;
    }

    int og  = t & 15;          // GEMM column group / lane-in-group
    int ng4 = (t >> 4) * 4;    // this thread/group's first node (local)
    int ll  = t & 15;

    // CSR ranges of owned nodes
    int i0[4], i1[4];
    #pragma unroll
    for (int j = 0; j < 4; j++) {
        int n = n0 + ng4 + j;
        if (n < N) { i0[j] = off[n]; i1[j] = off[n + 1]; }
        else       { i0[j] = 0; i1[j] = 0; }
    }
    float dacc[4] = {0.f, 0.f, 0.f, 0.f};

    for (int r = 0; r < NR; r++) {
        __syncthreads();   // protect As/ts from previous pass readers
        const float4* ag = (const float4*)(A + (size_t)r * DIM * DIM);
        float4* al = (float4*)&As[0][0];
        #pragma unroll
        for (int i = 0; i < 4; i++) al[t + 256 * i] = ag[t + 256 * i];
        __syncthreads();
        // t-tile GEMM: ts = qs @ A_r
        float4 a0 = make_float4(0.f,0.f,0.f,0.f), a1 = a0, a2 = a0, a3 = a0;
        #pragma unroll 8
        for (int d = 0; d < DIM; d++) {
            float4 wv = ((const float4*)&As[d][0])[og];
            float x0 = qs[ng4 + 0][d];
            float x1 = qs[ng4 + 1][d];
            float x2 = qs[ng4 + 2][d];
            float x3 = qs[ng4 + 3][d];
            a0.x = fmaf(x0, wv.x, a0.x); a0.y = fmaf(x0, wv.y, a0.y);
            a0.z = fmaf(x0, wv.z, a0.z); a0.w = fmaf(x0, wv.w, a0.w);
            a1.x = fmaf(x1, wv.x, a1.x); a1.y = fmaf(x1, wv.y, a1.y);
            a1.z = fmaf(x1, wv.z, a1.z); a1.w = fmaf(x1, wv.w, a1.w);
            a2.x = fmaf(x2, wv.x, a2.x); a2.y = fmaf(x2, wv.y, a2.y);
            a2.z = fmaf(x2, wv.z, a2.z); a2.w = fmaf(x2, wv.w, a2.w);
            a3.x = fmaf(x3, wv.x, a3.x); a3.y = fmaf(x3, wv.y, a3.y);
            a3.z = fmaf(x3, wv.z, a3.z); a3.w = fmaf(x3, wv.w, a3.w);
        }
        ((float4*)&ts[ng4 + 0][0])[og] = a0;
        ((float4*)&ts[ng4 + 1][0])[og] = a1;
        ((float4*)&ts[ng4 + 2][0])[og] = a2;
        ((float4*)&ts[ng4 + 3][0])[og] = a3;
        __syncthreads();
        // edge walk for relation r over owned nodes
        float pri = rel_pri[r] * 0.125f;
        #pragma unroll
        for (int j = 0; j < 4; j++) {
            float4 tv = ((const float4*)&ts[ng4 + j][0])[ll];
            for (int i = i0[j]; i < i1[j]; i++) {
                int sev = se[i];
                if ((sev >> 24) != r) continue;
                int s = sev & SRC_MASK;
                float4 kv = ((const float4*)(k + (size_t)s * DIM))[ll];
                float p = tv.x * kv.x + tv.y * kv.y + tv.z * kv.z + tv.w * kv.w;
                p += __shfl_xor(p, 8, 16);
                p += __shfl_xor(p, 4, 16);
                p += __shfl_xor(p, 2, 16);
                p += __shfl_xor(p, 1, 16);
                if (ll == 0) {
                    float e_ = expf(p * pri);   // logits tiny: no max-shift needed
                    ex[i] = e_;
                    dacc[j] += e_;
                }
            }
        }
    }
    if (ll == 0) {
        #pragma unroll
        for (int j = 0; j < 4; j++) {
            int n = n0 + ng4 + j;
            if (n < N) den[n] = dacc[j];
        }
    }
}

// ---- fused aggregate: y_r = sum alpha*v[s] in LDS, agg += y_r @ W_r in regs ----
__global__ void agg_fused(const float* __restrict__ v, const float* __restrict__ ex,
                          const int* __restrict__ se, const int* __restrict__ off,
                          const float* __restrict__ Mw, const float* __restrict__ den,
                          float* __restrict__ agg, int N) {
    __shared__ float ys[64][68];
    __shared__ float Wsm[64][64];
    int t  = threadIdx.x;
    int n0 = blockIdx.x * 64;
    int og  = t & 15;
    int ng4 = (t >> 4) * 4;
    int ll  = t & 15;

    int i0[4], i1[4];
    float inv[4];
    #pragma unroll
    for (int j = 0; j < 4; j++) {
        int n = n0 + ng4 + j;
        if (n < N) {
            i0[j] = off[n]; i1[j] = off[n + 1];
            float dn = den[n];
            inv[j] = (dn == 0.f) ? 0.f : 1.f / dn;
        } else { i0[j] = 0; i1[j] = 0; inv[j] = 0.f; }
    }

    float4 c0 = make_float4(0.f,0.f,0.f,0.f), c1 = c0, c2 = c0, c3 = c0;

    for (int r = 0; r < NR; r++) {
        __syncthreads();   // protect ys/Wsm from previous pass readers
        // stage W_msg_r
        const float4* wg = (const float4*)(Mw + (size_t)r * DIM * DIM);
        float4* wl = (float4*)&Wsm[0][0];
        #pragma unroll
        for (int i = 0; i < 4; i++) wl[t + 256 * i] = wg[t + 256 * i];
        // y accumulation for owned nodes (group exclusively owns its rows)
        #pragma unroll
        for (int j = 0; j < 4; j++) {
            float4 ya = make_float4(0.f, 0.f, 0.f, 0.f);
            float iv = inv[j];
            for (int i = i0[j]; i < i1[j]; i++) {
                int sev = se[i];
                if ((sev >> 24) != r) continue;
                int s = sev & SRC_MASK;
                float alpha = ex[i] * iv;
                float4 vv = ((const float4*)(v + (size_t)s * DIM))[ll];
                ya.x = fmaf(alpha, vv.x, ya.x);
                ya.y = fmaf(alpha, vv.y, ya.y);
                ya.z = fmaf(alpha, vv.z, ya.z);
                ya.w = fmaf(alpha, vv.w, ya.w);
            }
            ((float4*)&ys[ng4 + j][0])[ll] = ya;
        }
        __syncthreads();
        // agg += ys @ W_r
        #pragma unroll 8
        for (int d = 0; d < DIM; d++) {
            float4 wv = ((const float4*)&Wsm[d][0])[og];
            float x0 = ys[ng4 + 0][d];
            float x1 = ys[ng4 + 1][d];
            float x2 = ys[ng4 + 2][d];
            float x3 = ys[ng4 + 3][d];
            c0.x = fmaf(x0, wv.x, c0.x); c0.y = fmaf(x0, wv.y, c0.y);
            c0.z = fmaf(x0, wv.z, c0.z); c0.w = fmaf(x0, wv.w, c0.w);
            c1.x = fmaf(x1, wv.x, c1.x); c1.y = fmaf(x1, wv.y, c1.y);
            c1.z = fmaf(x1, wv.z, c1.z); c1.w = fmaf(x1, wv.w, c1.w);
            c2.x = fmaf(x2, wv.x, c2.x); c2.y = fmaf(x2, wv.y, c2.y);
            c2.z = fmaf(x2, wv.z, c2.z); c2.w = fmaf(x2, wv.w, c2.w);
            c3.x = fmaf(x3, wv.x, c3.x); c3.y = fmaf(x3, wv.y, c3.y);
            c3.z = fmaf(x3, wv.z, c3.z); c3.w = fmaf(x3, wv.w, c3.w);
        }
    }
    if (n0 + ng4 + 0 < N) ((float4*)(agg + (size_t)(n0 + ng4 + 0) * DIM))[og] = c0;
    if (n0 + ng4 + 1 < N) ((float4*)(agg + (size_t)(n0 + ng4 + 1) * DIM))[og] = c1;
    if (n0 + ng4 + 2 < N) ((float4*)(agg + (size_t)(n0 + ng4 + 2) * DIM))[og] = c2;
    if (n0 + ng4 + 3 < N) ((float4*)(agg + (size_t)(n0 + ng4 + 3) * DIM))[og] = c3;
}

// ------- typed output GEMM: 64-node tile, sigmoid(skip)*W staged in LDS -------
__global__ void out_typed(const float* __restrict__ agg, const int* __restrict__ ntype,
                          const int* __restrict__ order, const int* __restrict__ tm,
                          const float* __restrict__ Wa, const float* __restrict__ skip,
                          float* __restrict__ out, int N) {
    __shared__ float xs[64][68];
    __shared__ float wsm[64][64];
    int t  = threadIdx.x;
    int n0 = blockIdx.x * 64;
    if (n0 >= tm[12]) return;
    int first = order[n0];
    if (first < 0) return;
    int ty = ntype[first];
    float sg = 1.f / (1.f + expf(-skip[ty]));

    const float4* wg = (const float4*)(Wa + (size_t)ty * DIM * DIM);
    float4* wl = (float4*)&wsm[0][0];
    #pragma unroll
    for (int i = 0; i < 4; i++) {
        float4 w = wg[t + 256 * i];
        w.x *= sg; w.y *= sg; w.z *= sg; w.w *= sg;
        wl[t + 256 * i] = w;
    }
    #pragma unroll
    for (int i = 0; i < 4; i++) {
        int idx = t + 256 * i;
        int row = idx >> 4, c4 = idx & 15;
        int gn = order[n0 + row];
        float4 xv = make_float4(0.f, 0.f, 0.f, 0.f);
        if (gn >= 0) xv = ((const float4*)(agg + (size_t)gn * DIM))[c4];
        ((float4*)&xs[row][0])[c4] = xv;
    }
    __syncthreads();

    int og  = t & 15;
    int ng4 = (t >> 4) * 4;
    float4 a0 = make_float4(0.f,0.f,0.f,0.f), a1 = a0, a2 = a0, a3 = a0;
    #pragma unroll 8
    for (int d = 0; d < DIM; d++) {
        float4 wv = ((const float4*)&wsm[d][0])[og];
        float x0 = xs[ng4 + 0][d];
        float x1 = xs[ng4 + 1][d];
        float x2 = xs[ng4 + 2][d];
        float x3 = xs[ng4 + 3][d];
        a0.x = fmaf(x0, wv.x, a0.x); a0.y = fmaf(x0, wv.y, a0.y);
        a0.z = fmaf(x0, wv.z, a0.z); a0.w = fmaf(x0, wv.w, a0.w);
        a1.x = fmaf(x1, wv.x, a1.x); a1.y = fmaf(x1, wv.y, a1.y);
        a1.z = fmaf(x1, wv.z, a1.z); a1.w = fmaf(x1, wv.w, a1.w);
        a2.x = fmaf(x2, wv.x, a2.x); a2.y = fmaf(x2, wv.y, a2.y);
        a2.z = fmaf(x2, wv.z, a2.z); a2.w = fmaf(x2, wv.w, a2.w);
        a3.x = fmaf(x3, wv.x, a3.x); a3.y = fmaf(x3, wv.y, a3.y);
        a3.z = fmaf(x3, wv.z, a3.z); a3.w = fmaf(x3, wv.w, a3.w);
    }
    int g0 = order[n0 + ng4 + 0];
    int g1 = order[n0 + ng4 + 1];
    int g2 = order[n0 + ng4 + 2];
    int g3 = order[n0 + ng4 + 3];
    if (g0 >= 0) ((float4*)(out + (size_t)g0 * DIM))[og] = a0;
    if (g1 >= 0) ((float4*)(out + (size_t)g1 * DIM))[og] = a1;
    if (g2 >= 0) ((float4*)(out + (size_t)g2 * DIM))[og] = a2;
    if (g3 >= 0) ((float4*)(out + (size_t)g3 * DIM))[og] = a3;
}

extern "C" void kernel_launch(void* const* d_in, const int* in_sizes, int n_in,
                              void* d_out, int out_size, void* d_ws, size_t ws_size,
                              hipStream_t stream) {
    const float* h       = (const float*)d_in[0];
    const int*   ntype   = (const int*)  d_in[1];
    const int*   src     = (const int*)  d_in[2];
    const int*   dst     = (const int*)  d_in[3];
    const int*   et      = (const int*)  d_in[4];
    const float* k_lin   = (const float*)d_in[5];
    const float* q_lin   = (const float*)d_in[6];
    const float* v_lin   = (const float*)d_in[7];
    const float* a_lin   = (const float*)d_in[8];
    const float* rel_att = (const float*)d_in[9];
    const float* rel_msg = (const float*)d_in[10];
    const float* rel_pri = (const float*)d_in[11];
    const float* skip    = (const float*)d_in[12];

    int N = in_sizes[1];
    int E = in_sizes[2];
    int ocap = N + NT * 64;

    float* ws = (float*)d_ws;
    size_t o = 0;
    float* k     = ws + o; o += (size_t)N * DIM;
    float* q     = ws + o; o += (size_t)N * DIM;
    float* v     = ws + o; o += (size_t)N * DIM;
    float* ex    = ws + o; o += (size_t)E;
    float* den   = ws + o; o += (size_t)N;
    int*   off   = (int*)(ws + o); o += (size_t)N + 1;
    int*   cnt   = (int*)(ws + o); o += (size_t)N;
    int*   cnt2  = (int*)(ws + o); o += (size_t)N;
    int*   se    = (int*)(ws + o); o += (size_t)E;
    int*   bsum  = (int*)(ws + o); o += 1024;
    int*   order = (int*)(ws + o); o += (size_t)ocap;
    int*   tm    = (int*)(ws + o); o += 16;
    float* agg   = k;   // k dead after score phase

    float* out = (float*)d_out;

    // ---- type sort ----
    init_order<<<(ocap + 255) / 256, 256, 0, stream>>>(order, tm, ocap);
    type_count<<<(N + 255) / 256, 256, 0, stream>>>(ntype, tm, N);
    type_scan<<<1, 64, 0, stream>>>(tm);
    type_scatter<<<(N + 255) / 256, 256, 0, stream>>>(ntype, tm, order, N);

    // ---- typed fused projections ----
    int gridP = (N + NT * 64 + 63) / 64;
    proj_typed<<<gridP, 256, 0, stream>>>(h, ntype, order, tm, k_lin, q_lin, v_lin,
                                          k, q, v, N);

    // ---- CSR build ----
    init_cnt<<<(N + 255) / 256, 256, 0, stream>>>(cnt, cnt2, N);
    hist_kernel<<<(E + 255) / 256, 256, 0, stream>>>(dst, cnt, E);
    int nb = (N + 1023) / 1024;
    scan1<<<nb, 1024, 0, stream>>>(cnt, off, bsum, N);
    scan2<<<1, 1024, 0, stream>>>(bsum, nb);
    scan3<<<nb, 1024, 0, stream>>>(off, bsum, N, E);
    scatter_kernel<<<(E + 255) / 256, 256, 0, stream>>>(src, dst, et, off, cnt2, se, E);

    // ---- fused score + aggregate ----
    int nb64 = (N + 63) / 64;
    score_fused<<<nb64, 256, 0, stream>>>(q, k, se, off, rel_att, rel_pri, ex, den, N);
    agg_fused<<<nb64, 256, 0, stream>>>(v, ex, se, off, rel_msg, den, agg, N);

    // ---- typed output GEMM ----
    out_typed<<<gridP, 256, 0, stream>>>(agg, ntype, order, tm, a_lin, skip, out, N);
}

// Round 8
// 896.037 us; speedup vs baseline: 2.1228x; 2.1228x over previous
//
#include <hip/hip_runtime.h>
#include <math.h>

#define DIM 64
#define NT 4
#define NR 8
#define SRC_MASK 0x00FFFFFF
// tmeta layout: [0..3]=tcnt  [4..7]=tbase  [8..11]=tfill  [12]=padded_total

// ---- bf16 helpers (bit-level; values are finite/small) ----
__device__ __forceinline__ unsigned short f2bf(float f) {
    unsigned u = __float_as_uint(f);
    return (unsigned short)((u + 0x7FFF + ((u >> 16) & 1)) >> 16);  // RNE
}
__device__ __forceinline__ float4 bf4_to_f4(ushort4 u) {
    float4 f;
    f.x = __uint_as_float((unsigned)u.x << 16);
    f.y = __uint_as_float((unsigned)u.y << 16);
    f.z = __uint_as_float((unsigned)u.z << 16);
    f.w = __uint_as_float((unsigned)u.w << 16);
    return f;
}

__global__ void zero_f(float* __restrict__ p, int n) {
    int i = blockIdx.x * blockDim.x + threadIdx.x;
    if (i < n) p[i] = 0.f;
}

__global__ void init_cnt(int* __restrict__ cnt, int* __restrict__ cnt2, int N) {
    int i = blockIdx.x * blockDim.x + threadIdx.x;
    if (i < N) { cnt[i] = 0; cnt2[i] = 0; }
}

__global__ void init_order(int* __restrict__ order, int* __restrict__ tm, int cap) {
    int i = blockIdx.x * blockDim.x + threadIdx.x;
    if (i < cap) order[i] = -1;
    if (i < 16) tm[i] = 0;
}

// ---- per-wave ballot histogram of node types ----
__global__ void type_count(const int* __restrict__ ntype, int* __restrict__ tm, int N) {
    int i = blockIdx.x * blockDim.x + threadIdx.x;
    int t = (i < N) ? ntype[i] : -1;
    int lane = threadIdx.x & 63;
    #pragma unroll
    for (int tt = 0; tt < NT; tt++) {
        unsigned long long m = __ballot(t == tt);
        int c = __popcll(m);
        if (c && lane == (__ffsll((long long)m) - 1)) atomicAdd(&tm[tt], c);
    }
}

__global__ void type_scan(int* __restrict__ tm) {
    if (threadIdx.x == 0 && blockIdx.x == 0) {
        int b = 0;
        for (int t = 0; t < NT; t++) { tm[4 + t] = b; b += ((tm[t] + 63) >> 6) << 6; }
        tm[12] = b;
    }
}

__global__ void type_scatter(const int* __restrict__ ntype, int* __restrict__ tm,
                             int* __restrict__ order, int N) {
    int i = blockIdx.x * blockDim.x + threadIdx.x;
    int t = (i < N) ? ntype[i] : -1;
    int lane = threadIdx.x & 63;
    #pragma unroll
    for (int tt = 0; tt < NT; tt++) {
        unsigned long long m = __ballot(t == tt);
        int c = __popcll(m);
        if (!c) continue;
        int ldr = __ffsll((long long)m) - 1;
        int base = 0;
        if (lane == ldr) base = atomicAdd(&tm[8 + tt], c);
        base = __shfl(base, ldr, 64);
        if (t == tt) {
            int rank = __popcll(m & ((1ull << lane) - 1ull));
            order[tm[4 + tt] + base + rank] = i;
        }
    }
}

// ---- typed K/Q/V projection: 64-node tile, one 16KB W buffer, loop 3 mats ----
__global__ void proj_typed(const float* __restrict__ h, const int* __restrict__ ntype,
                           const int* __restrict__ order, const int* __restrict__ tm,
                           const float* __restrict__ Wk, const float* __restrict__ Wq,
                           const float* __restrict__ Wv,
                           float* __restrict__ k, float* __restrict__ q,
                           float* __restrict__ v, int N) {
    __shared__ float xs[64][68];
    __shared__ float wsm[64][64];
    int t  = threadIdx.x;
    int n0 = blockIdx.x * 64;
    if (n0 >= tm[12]) return;
    int first = order[n0];
    if (first < 0) return;
    int ty = ntype[first];

    #pragma unroll
    for (int i = 0; i < 4; i++) {
        int idx = t + 256 * i;
        int row = idx >> 4, c4 = idx & 15;
        int gn = order[n0 + row];
        float4 xv = make_float4(0.f, 0.f, 0.f, 0.f);
        if (gn >= 0) xv = ((const float4*)(h + (size_t)gn * DIM))[c4];
        ((float4*)&xs[row][0])[c4] = xv;
    }

    const float* Ws[3] = { Wk + (size_t)ty * DIM * DIM,
                           Wq + (size_t)ty * DIM * DIM,
                           Wv + (size_t)ty * DIM * DIM };
    float* outs[3] = { k, q, v };

    int og  = t & 15;
    int ng4 = (t >> 4) * 4;
    int g0 = order[n0 + ng4 + 0];
    int g1 = order[n0 + ng4 + 1];
    int g2 = order[n0 + ng4 + 2];
    int g3 = order[n0 + ng4 + 3];

    for (int mm = 0; mm < 3; mm++) {
        const float4* wg = (const float4*)Ws[mm];
        float4* wl = (float4*)&wsm[0][0];
        __syncthreads();
        #pragma unroll
        for (int i = 0; i < 4; i++) wl[t + 256 * i] = wg[t + 256 * i];
        __syncthreads();
        float4 a0 = make_float4(0.f,0.f,0.f,0.f), a1 = a0, a2 = a0, a3 = a0;
        #pragma unroll 8
        for (int d = 0; d < DIM; d++) {
            float4 wv = ((const float4*)&wsm[d][0])[og];
            float x0 = xs[ng4 + 0][d];
            float x1 = xs[ng4 + 1][d];
            float x2 = xs[ng4 + 2][d];
            float x3 = xs[ng4 + 3][d];
            a0.x = fmaf(x0, wv.x, a0.x); a0.y = fmaf(x0, wv.y, a0.y);
            a0.z = fmaf(x0, wv.z, a0.z); a0.w = fmaf(x0, wv.w, a0.w);
            a1.x = fmaf(x1, wv.x, a1.x); a1.y = fmaf(x1, wv.y, a1.y);
            a1.z = fmaf(x1, wv.z, a1.z); a1.w = fmaf(x1, wv.w, a1.w);
            a2.x = fmaf(x2, wv.x, a2.x); a2.y = fmaf(x2, wv.y, a2.y);
            a2.z = fmaf(x2, wv.z, a2.z); a2.w = fmaf(x2, wv.w, a2.w);
            a3.x = fmaf(x3, wv.x, a3.x); a3.y = fmaf(x3, wv.y, a3.y);
            a3.z = fmaf(x3, wv.z, a3.z); a3.w = fmaf(x3, wv.w, a3.w);
        }
        float* ob = outs[mm];
        if (g0 >= 0) ((float4*)(ob + (size_t)g0 * DIM))[og] = a0;
        if (g1 >= 0) ((float4*)(ob + (size_t)g1 * DIM))[og] = a1;
        if (g2 >= 0) ((float4*)(ob + (size_t)g2 * DIM))[og] = a2;
        if (g3 >= 0) ((float4*)(ob + (size_t)g3 * DIM))[og] = a3;
    }
}

// ---------------- CSR build ----------------
__global__ void hist_kernel(const int* __restrict__ dst, int* __restrict__ cnt, int E) {
    int e = blockIdx.x * blockDim.x + threadIdx.x;
    if (e < E) atomicAdd(&cnt[dst[e]], 1);
}

__global__ void scan1(const int* __restrict__ cnt, int* __restrict__ off,
                      int* __restrict__ bsum, int N) {
    __shared__ int buf[1024];
    int tid = threadIdx.x;
    int i = blockIdx.x * 1024 + tid;
    int x = (i < N) ? cnt[i] : 0;
    buf[tid] = x;
    __syncthreads();
    for (int s = 1; s < 1024; s <<= 1) {
        int t = (tid >= s) ? buf[tid - s] : 0;
        __syncthreads();
        buf[tid] += t;
        __syncthreads();
    }
    if (i < N) off[i] = buf[tid] - x;
    if (tid == 1023) bsum[blockIdx.x] = buf[1023];
}

__global__ void scan2(int* __restrict__ bsum, int nb) {
    __shared__ int buf[1024];
    __shared__ int carry;
    int tid = threadIdx.x;
    if (tid == 0) carry = 0;
    __syncthreads();
    for (int base = 0; base < nb; base += 1024) {
        int i = base + tid;
        int x = (i < nb) ? bsum[i] : 0;
        buf[tid] = x;
        __syncthreads();
        for (int s = 1; s < 1024; s <<= 1) {
            int t = (tid >= s) ? buf[tid - s] : 0;
            __syncthreads();
            buf[tid] += t;
            __syncthreads();
        }
        if (i < nb) bsum[i] = carry + buf[tid] - x;
        __syncthreads();
        if (tid == 1023) carry += buf[1023];
        __syncthreads();
    }
}

__global__ void scan3(int* __restrict__ off, const int* __restrict__ bsum, int N, int E) {
    int i = blockIdx.x * 1024 + threadIdx.x;
    if (i < N) off[i] += bsum[blockIdx.x];
    if (i == 0) off[N] = E;
}

__global__ void scatter_kernel(const int* __restrict__ src, const int* __restrict__ dst,
                               const int* __restrict__ et, const int* __restrict__ off,
                               int* __restrict__ cnt2, int* __restrict__ se, int E) {
    int e = blockIdx.x * blockDim.x + threadIdx.x;
    if (e >= E) return;
    int d = dst[e];
    int p = off[d] + atomicAdd(&cnt2[d], 1);
    se[p] = (et[e] << 24) | src[e];
}

// ------- apply_rel: LDS-blocked GEMM, 64x64 tile, OUTPUT IN BF16 -------
__global__ void apply_rel_gemm(const float* __restrict__ x, const float* __restrict__ Wr,
                               unsigned short* __restrict__ out, int N, int r0) {
    __shared__ float xs[64][68];
    __shared__ float wsm[64][64];
    int t  = threadIdx.x;
    int r  = r0 + blockIdx.y;
    int n0 = blockIdx.x * 64;

    const float4* wg = (const float4*)(Wr + (size_t)r * DIM * DIM);
    float4* wl = (float4*)&wsm[0][0];
    #pragma unroll
    for (int i = 0; i < 4; i++) wl[t + 256 * i] = wg[t + 256 * i];
    #pragma unroll
    for (int i = 0; i < 4; i++) {
        int idx = t + 256 * i;
        int row = idx >> 4, c4 = idx & 15;
        int gn = n0 + row;
        float4 xv = make_float4(0.f, 0.f, 0.f, 0.f);
        if (gn < N) xv = ((const float4*)(x + (size_t)gn * DIM))[c4];
        ((float4*)&xs[row][0])[c4] = xv;
    }
    __syncthreads();

    int og  = t & 15;
    int ng4 = (t >> 4) * 4;
    float4 a0 = make_float4(0.f,0.f,0.f,0.f), a1 = a0, a2 = a0, a3 = a0;
    #pragma unroll 8
    for (int d = 0; d < DIM; d++) {
        float4 wv = ((const float4*)&wsm[d][0])[og];
        float x0 = xs[ng4 + 0][d];
        float x1 = xs[ng4 + 1][d];
        float x2 = xs[ng4 + 2][d];
        float x3 = xs[ng4 + 3][d];
        a0.x = fmaf(x0, wv.x, a0.x); a0.y = fmaf(x0, wv.y, a0.y);
        a0.z = fmaf(x0, wv.z, a0.z); a0.w = fmaf(x0, wv.w, a0.w);
        a1.x = fmaf(x1, wv.x, a1.x); a1.y = fmaf(x1, wv.y, a1.y);
        a1.z = fmaf(x1, wv.z, a1.z); a1.w = fmaf(x1, wv.w, a1.w);
        a2.x = fmaf(x2, wv.x, a2.x); a2.y = fmaf(x2, wv.y, a2.y);
        a2.z = fmaf(x2, wv.z, a2.z); a2.w = fmaf(x2, wv.w, a2.w);
        a3.x = fmaf(x3, wv.x, a3.x); a3.y = fmaf(x3, wv.y, a3.y);
        a3.z = fmaf(x3, wv.z, a3.z); a3.w = fmaf(x3, wv.w, a3.w);
    }
    unsigned short* ob = out + (size_t)blockIdx.y * N * DIM;
    ushort4 b0 = make_ushort4(f2bf(a0.x), f2bf(a0.y), f2bf(a0.z), f2bf(a0.w));
    ushort4 b1 = make_ushort4(f2bf(a1.x), f2bf(a1.y), f2bf(a1.z), f2bf(a1.w));
    ushort4 b2 = make_ushort4(f2bf(a2.x), f2bf(a2.y), f2bf(a2.z), f2bf(a2.w));
    ushort4 b3 = make_ushort4(f2bf(a3.x), f2bf(a3.y), f2bf(a3.z), f2bf(a3.w));
    if (n0 + ng4 + 0 < N) ((ushort4*)(ob + (size_t)(n0 + ng4 + 0) * DIM))[og] = b0;
    if (n0 + ng4 + 1 < N) ((ushort4*)(ob + (size_t)(n0 + ng4 + 1) * DIM))[og] = b1;
    if (n0 + ng4 + 2 < N) ((ushort4*)(ob + (size_t)(n0 + ng4 + 2) * DIM))[og] = b2;
    if (n0 + ng4 + 3 < N) ((ushort4*)(ob + (size_t)(n0 + ng4 + 3) * DIM))[og] = b3;
}

// ------- score over CSR (+fused den): 16-lane group per dst node, bf16 qW -------
__global__ void score_csr(const unsigned short* __restrict__ qW, const float* __restrict__ k,
                          const int* __restrict__ se, const int* __restrict__ off,
                          const float* __restrict__ rel_pri,
                          float* __restrict__ ex, float* __restrict__ den,
                          int N, int r0, int r1) {
    int n  = blockIdx.x * 16 + (threadIdx.x >> 4);
    int ll = threadIdx.x & 15;
    if (n >= N) return;
    int i0 = off[n], i1 = off[n + 1];
    float dl = 0.f;
    for (int i = i0; i < i1; i++) {
        int sev = se[i];
        int r = sev >> 24;
        if (r < r0 || r >= r1) continue;
        int s = sev & SRC_MASK;
        ushort4 ua = ((const ushort4*)(qW + ((size_t)(r - r0) * N + n) * DIM))[ll];
        float4 a = bf4_to_f4(ua);
        float4 b = ((const float4*)(k + (size_t)s * DIM))[ll];
        float p = a.x * b.x + a.y * b.y + a.z * b.z + a.w * b.w;
        p += __shfl_xor(p, 8, 16);
        p += __shfl_xor(p, 4, 16);
        p += __shfl_xor(p, 2, 16);
        p += __shfl_xor(p, 1, 16);
        if (ll == 0) {
            float e_ = expf(p * rel_pri[r] * 0.125f);  // logits tiny: no max-shift
            ex[i] = e_;
            dl += e_;
        }
    }
    if (ll == 0) den[n] = (r0 == 0) ? dl : den[n] + dl;
}

// ------- aggregate over CSR: 16-lane group per dst node, bf16 vW -------
__global__ void agg_csr(const unsigned short* __restrict__ vW, const float* __restrict__ ex,
                        const int* __restrict__ se, const int* __restrict__ off,
                        const float* __restrict__ den, float* __restrict__ agg,
                        int N, int r0, int r1, int first) {
    int n  = blockIdx.x * 16 + (threadIdx.x >> 4);
    int ll = threadIdx.x & 15;
    if (n >= N) return;
    int i0 = off[n], i1 = off[n + 1];
    float dn = den[n];
    float inv = (dn == 0.f) ? 0.f : 1.f / dn;
    float4 acc = make_float4(0.f, 0.f, 0.f, 0.f);
    for (int i = i0; i < i1; i++) {
        int sev = se[i];
        int r = sev >> 24;
        if (r < r0 || r >= r1) continue;
        int s = sev & SRC_MASK;
        float alpha = ex[i] * inv;
        ushort4 um = ((const ushort4*)(vW + ((size_t)(r - r0) * N + s) * DIM))[ll];
        float4 mv = bf4_to_f4(um);
        acc.x = fmaf(alpha, mv.x, acc.x);
        acc.y = fmaf(alpha, mv.y, acc.y);
        acc.z = fmaf(alpha, mv.z, acc.z);
        acc.w = fmaf(alpha, mv.w, acc.w);
    }
    float4* ap = (float4*)(agg + (size_t)n * DIM) + ll;
    if (first) *ap = acc;
    else {
        float4 o = *ap;
        o.x += acc.x; o.y += acc.y; o.z += acc.z; o.w += acc.w;
        *ap = o;
    }
}

// ------- typed output GEMM: 64-node tile, sigmoid(skip)*W staged in LDS -------
__global__ void out_typed(const float* __restrict__ agg, const int* __restrict__ ntype,
                          const int* __restrict__ order, const int* __restrict__ tm,
                          const float* __restrict__ Wa, const float* __restrict__ skip,
                          float* __restrict__ out, int N) {
    __shared__ float xs[64][68];
    __shared__ float wsm[64][64];
    int t  = threadIdx.x;
    int n0 = blockIdx.x * 64;
    if (n0 >= tm[12]) return;
    int first = order[n0];
    if (first < 0) return;
    int ty = ntype[first];
    float sg = 1.f / (1.f + expf(-skip[ty]));

    const float4* wg = (const float4*)(Wa + (size_t)ty * DIM * DIM);
    float4* wl = (float4*)&wsm[0][0];
    #pragma unroll
    for (int i = 0; i < 4; i++) {
        float4 w = wg[t + 256 * i];
        w.x *= sg; w.y *= sg; w.z *= sg; w.w *= sg;
        wl[t + 256 * i] = w;
    }
    #pragma unroll
    for (int i = 0; i < 4; i++) {
        int idx = t + 256 * i;
        int row = idx >> 4, c4 = idx & 15;
        int gn = order[n0 + row];
        float4 xv = make_float4(0.f, 0.f, 0.f, 0.f);
        if (gn >= 0) xv = ((const float4*)(agg + (size_t)gn * DIM))[c4];
        ((float4*)&xs[row][0])[c4] = xv;
    }
    __syncthreads();

    int og  = t & 15;
    int ng4 = (t >> 4) * 4;
    float4 a0 = make_float4(0.f,0.f,0.f,0.f), a1 = a0, a2 = a0, a3 = a0;
    #pragma unroll 8
    for (int d = 0; d < DIM; d++) {
        float4 wv = ((const float4*)&wsm[d][0])[og];
        float x0 = xs[ng4 + 0][d];
        float x1 = xs[ng4 + 1][d];
        float x2 = xs[ng4 + 2][d];
        float x3 = xs[ng4 + 3][d];
        a0.x = fmaf(x0, wv.x, a0.x); a0.y = fmaf(x0, wv.y, a0.y);
        a0.z = fmaf(x0, wv.z, a0.z); a0.w = fmaf(x0, wv.w, a0.w);
        a1.x = fmaf(x1, wv.x, a1.x); a1.y = fmaf(x1, wv.y, a1.y);
        a1.z = fmaf(x1, wv.z, a1.z); a1.w = fmaf(x1, wv.w, a1.w);
        a2.x = fmaf(x2, wv.x, a2.x); a2.y = fmaf(x2, wv.y, a2.y);
        a2.z = fmaf(x2, wv.z, a2.z); a2.w = fmaf(x2, wv.w, a2.w);
        a3.x = fmaf(x3, wv.x, a3.x); a3.y = fmaf(x3, wv.y, a3.y);
        a3.z = fmaf(x3, wv.z, a3.z); a3.w = fmaf(x3, wv.w, a3.w);
    }
    int g0 = order[n0 + ng4 + 0];
    int g1 = order[n0 + ng4 + 1];
    int g2 = order[n0 + ng4 + 2];
    int g3 = order[n0 + ng4 + 3];
    if (g0 >= 0) ((float4*)(out + (size_t)g0 * DIM))[og] = a0;
    if (g1 >= 0) ((float4*)(out + (size_t)g1 * DIM))[og] = a1;
    if (g2 >= 0) ((float4*)(out + (size_t)g2 * DIM))[og] = a2;
    if (g3 >= 0) ((float4*)(out + (size_t)g3 * DIM))[og] = a3;
}

// ------- fallback (tiny ws): per-edge bilinear with atomics -------
__global__ void score_direct(const float* __restrict__ q, const float* __restrict__ k,
                             const int* __restrict__ src, const int* __restrict__ dst,
                             const int* __restrict__ et, const float* __restrict__ A,
                             const float* __restrict__ rel_pri,
                             float* __restrict__ ex, float* __restrict__ den, int E) {
    int e = (blockIdx.x * blockDim.x + threadIdx.x) >> 6;
    int l = threadIdx.x & 63;
    if (e >= E) return;
    int s = src[e], d = dst[e], r = et[e];
    float qv = q[(size_t)d * DIM + l];
    const float* a = A + (size_t)r * DIM * DIM;
    float t = 0.f;
    #pragma unroll 16
    for (int dd = 0; dd < DIM; dd++)
        t = fmaf(__shfl(qv, dd, 64), a[dd * DIM + l], t);
    float p = t * k[(size_t)s * DIM + l];
    #pragma unroll
    for (int off = 32; off > 0; off >>= 1) p += __shfl_xor(p, off, 64);
    if (l == 0) {
        float e_ = expf(p * rel_pri[r] * 0.125f);
        ex[e] = e_;
        atomicAdd(&den[d], e_);
    }
}

__global__ void agg_direct(const float* __restrict__ v, const float* __restrict__ ex,
                           const int* __restrict__ src, const int* __restrict__ dst,
                           const int* __restrict__ et, const float* __restrict__ Mw,
                           const float* __restrict__ den,
                           float* __restrict__ agg, int E) {
    int e = (blockIdx.x * blockDim.x + threadIdx.x) >> 6;
    int l = threadIdx.x & 63;
    if (e >= E) return;
    int s = src[e], d = dst[e], r = et[e];
    float vv = v[(size_t)s * DIM + l];
    const float* w = Mw + (size_t)r * DIM * DIM;
    float t = 0.f;
    #pragma unroll 16
    for (int dd = 0; dd < DIM; dd++)
        t = fmaf(__shfl(vv, dd, 64), w[dd * DIM + l], t);
    float dn = den[d];
    float alpha = ex[e] / (dn == 0.f ? 1.f : dn);
    atomicAdd(&agg[(size_t)d * DIM + l], alpha * t);
}

extern "C" void kernel_launch(void* const* d_in, const int* in_sizes, int n_in,
                              void* d_out, int out_size, void* d_ws, size_t ws_size,
                              hipStream_t stream) {
    const float* h       = (const float*)d_in[0];
    const int*   ntype   = (const int*)  d_in[1];
    const int*   src     = (const int*)  d_in[2];
    const int*   dst     = (const int*)  d_in[3];
    const int*   et      = (const int*)  d_in[4];
    const float* k_lin   = (const float*)d_in[5];
    const float* q_lin   = (const float*)d_in[6];
    const float* v_lin   = (const float*)d_in[7];
    const float* a_lin   = (const float*)d_in[8];
    const float* rel_att = (const float*)d_in[9];
    const float* rel_msg = (const float*)d_in[10];
    const float* rel_pri = (const float*)d_in[11];
    const float* skip    = (const float*)d_in[12];

    int N = in_sizes[1];
    int E = in_sizes[2];
    int ocap = N + NT * 64;

    float* ws = (float*)d_ws;
    size_t o = 0;
    float* k     = ws + o; o += (size_t)N * DIM;
    float* q     = ws + o; o += (size_t)N * DIM;
    float* v     = ws + o; o += (size_t)N * DIM;
    float* ex    = ws + o; o += (size_t)E;
    float* den   = ws + o; o += (size_t)N;
    int*   off   = (int*)(ws + o); o += (size_t)N + 1;
    int*   cnt   = (int*)(ws + o); o += (size_t)N;
    int*   cnt2  = (int*)(ws + o); o += (size_t)N;
    int*   se    = (int*)(ws + o); o += (size_t)E;
    int*   bsum  = (int*)(ws + o); o += 1024;
    int*   order = (int*)(ws + o); o += (size_t)ocap;
    int*   tm    = (int*)(ws + o); o += 16;
    size_t fixed = o;
    float* agg = k;   // k dead after score phase

    size_t ws_floats = ws_size / sizeof(float);
    size_t avail = (ws_floats > fixed) ? (ws_floats - fixed) : 0;
    // bf16 chunk buffer: one relation tile = N*DIM ushorts = N*DIM/2 floats
    int C = (int)((avail * 2) / ((size_t)N * DIM));
    if (C > NR) C = NR;
    unsigned short* rbuf = (unsigned short*)(ws + fixed);

    float* out = (float*)d_out;

    // ---- type sort ----
    init_order<<<(ocap + 255) / 256, 256, 0, stream>>>(order, tm, ocap);
    type_count<<<(N + 255) / 256, 256, 0, stream>>>(ntype, tm, N);
    type_scan<<<1, 64, 0, stream>>>(tm);
    type_scatter<<<(N + 255) / 256, 256, 0, stream>>>(ntype, tm, order, N);

    // ---- typed fused projections ----
    int gridP = (N + NT * 64 + 63) / 64;
    proj_typed<<<gridP, 256, 0, stream>>>(h, ntype, order, tm, k_lin, q_lin, v_lin,
                                          k, q, v, N);

    if (C >= 1) {
        // ---- CSR build ----
        init_cnt<<<(N + 255) / 256, 256, 0, stream>>>(cnt, cnt2, N);
        hist_kernel<<<(E + 255) / 256, 256, 0, stream>>>(dst, cnt, E);
        int nb = (N + 1023) / 1024;
        scan1<<<nb, 1024, 0, stream>>>(cnt, off, bsum, N);
        scan2<<<1, 1024, 0, stream>>>(bsum, nb);
        scan3<<<nb, 1024, 0, stream>>>(off, bsum, N, E);
        scatter_kernel<<<(E + 255) / 256, 256, 0, stream>>>(src, dst, et, off, cnt2, se, E);

        int nb16 = (N + 15) / 16;
        int nb64 = (N + 63) / 64;
        for (int r0 = 0; r0 < NR; r0 += C) {
            int r1 = r0 + C < NR ? r0 + C : NR;
            apply_rel_gemm<<<dim3(nb64, r1 - r0), 256, 0, stream>>>(q, rel_att, rbuf, N, r0);
            score_csr<<<nb16, 256, 0, stream>>>(rbuf, k, se, off, rel_pri, ex, den, N, r0, r1);
        }
        for (int r0 = 0; r0 < NR; r0 += C) {
            int r1 = r0 + C < NR ? r0 + C : NR;
            apply_rel_gemm<<<dim3(nb64, r1 - r0), 256, 0, stream>>>(v, rel_msg, rbuf, N, r0);
            agg_csr<<<nb16, 256, 0, stream>>>(rbuf, ex, se, off, den, agg, N, r0, r1,
                                              r0 == 0 ? 1 : 0);
        }
    } else {
        // ---- workspace-starved fallback ----
        zero_f<<<(N + 255) / 256, 256, 0, stream>>>(den, N);
        score_direct<<<(E + 3) / 4, 256, 0, stream>>>(q, k, src, dst, et, rel_att, rel_pri,
                                                      ex, den, E);
        zero_f<<<(N * DIM + 255) / 256, 256, 0, stream>>>(agg, N * DIM);
        agg_direct<<<(E + 3) / 4, 256, 0, stream>>>(v, ex, src, dst, et, rel_msg,
                                                    den, agg, E);
    }

    // ---- typed output GEMM ----
    out_typed<<<gridP, 256, 0, stream>>>(agg, ntype, order, tm, a_lin, skip, out, N);
}